// Round 8
// baseline (312.002 us; speedup 1.0000x reference)
//
#include <hip/hip_runtime.h>

// QRNN fo-pooling, single fused kernel, minimal HBM traffic (read Y once).
// c_t = ff*c_{t-1} + gg, ff = sigmoid(F), gg = (1-ff)*tanh(Z), h_t = sigmoid(O)*c_t
// In-block chunked linear scan: 128 chunks x 4 steps cover T=512.
// Phase 1: per-thread chunk affine (A,B) over 4 channels; retain ff,gg (32 VGPR).
// Combine: Hillis-Steele scan over chunk affines in LDS (7 rounds, all threads).
// Phase 2: replay from registers; only O is loaded (first touch); write h.

#define T_SEQ 512
#define BATCH 32
#define HID   1024
#define CH    (BATCH * HID)        // 32768 channels
#define CH4   (CH / 4)             // 8192 float4 groups
#define HID4  (HID / 4)            // 256
#define ROWS4 (BATCH * 3 * HID4)   // float4 per t-step of Y (24576)
#define NC    128                  // chunks per block (time split)
#define CL    (T_SEQ / NC)         // 4 steps per chunk
#define JW    8                    // float4 channel-groups per block (32 channels)
#define NTHR  (NC * JW)            // 1024 threads

__device__ __forceinline__ float fast_sigmoid(float x) {
    float e = __builtin_amdgcn_exp2f(-1.4426950408889634f * x);
    return __builtin_amdgcn_rcpf(1.0f + e);
}
__device__ __forceinline__ float fast_tanh(float x) {
    float e = __builtin_amdgcn_exp2f(-2.8853900817779268f * x);
    float s = __builtin_amdgcn_rcpf(1.0f + e);
    return __builtin_fmaf(2.0f, s, -1.0f);
}
__device__ __forceinline__ float4 sig4(float4 v) {
    return make_float4(fast_sigmoid(v.x), fast_sigmoid(v.y),
                       fast_sigmoid(v.z), fast_sigmoid(v.w));
}
__device__ __forceinline__ float4 fma4(float4 a, float4 b, float4 c) {
    return make_float4(__builtin_fmaf(a.x, b.x, c.x), __builtin_fmaf(a.y, b.y, c.y),
                       __builtin_fmaf(a.z, b.z, c.z), __builtin_fmaf(a.w, b.w, c.w));
}

__global__ __launch_bounds__(NTHR) void fo_pool_fused(
        const float4* __restrict__ Y4,
        const float4* __restrict__ init_c4,
        const float4* __restrict__ init_h4,
        float4* __restrict__ out4) {
    __shared__ float4 sA[NC][JW];   // 16 KB — chunk affine A, then inclusive scan
    __shared__ float4 sB[NC][JW];   // 16 KB — chunk affine B, then inclusive scan

    const int tid = threadIdx.x;
    const int k   = tid >> 3;            // chunk index [0,128)
    const int j   = tid & (JW - 1);      // channel-group within block [0,8)
    const int c4  = blockIdx.x * JW + j; // global float4 channel group
    const int b   = c4 >> 8;             // / HID4
    const int h4  = c4 & (HID4 - 1);
    const float4* yb = Y4 + b * (3 * HID4) + h4 + (size_t)(k * CL) * ROWS4;

    // ---------------- Phase 1: chunk-local affine, retain ff/gg ------------
    float4 fr[CL], zr[CL];
#pragma unroll
    for (int t = 0; t < CL; ++t) {       // 8 independent loads up-front
        const float4* p = yb + (size_t)t * ROWS4;
        fr[t] = p[0]; zr[t] = p[HID4];
    }
    float4 ff[CL], gg[CL];
    float4 A  = make_float4(1.f, 1.f, 1.f, 1.f);
    float4 Bv = make_float4(0.f, 0.f, 0.f, 0.f);
#pragma unroll
    for (int t = 0; t < CL; ++t) {
        float4 s = sig4(fr[t]);
        float4 g;
        g.x = (1.f - s.x) * fast_tanh(zr[t].x);
        g.y = (1.f - s.y) * fast_tanh(zr[t].y);
        g.z = (1.f - s.z) * fast_tanh(zr[t].z);
        g.w = (1.f - s.w) * fast_tanh(zr[t].w);
        ff[t] = s; gg[t] = g;
        Bv = fma4(s, Bv, g);
        A.x *= s.x; A.y *= s.y; A.z *= s.z; A.w *= s.w;
    }
    sA[k][j] = A;
    sB[k][j] = Bv;
    __syncthreads();

    // ---------------- Combine: Hillis-Steele inclusive scan over chunks ----
    // Compose: (cur ∘ prev)(x) = curA*(prevA*x + prevB) + curB
#pragma unroll
    for (int d = 1; d < NC; d <<= 1) {
        float4 pa, pb;
        const bool has = (k >= d);
        if (has) { pa = sA[k - d][j]; pb = sB[k - d][j]; }
        __syncthreads();
        if (has) {
            float4 a  = sA[k][j];
            float4 bb = sB[k][j];
            sA[k][j] = make_float4(a.x * pa.x, a.y * pa.y, a.z * pa.z, a.w * pa.w);
            sB[k][j] = fma4(a, pb, bb);
        }
        __syncthreads();
    }

    // c_start for chunk k = (k==0) ? c0 : S_{k-1}(c0)
    const float4 c0 = init_c4[c4];
    float4 c;
    if (k == 0) {
        c = c0;
        out4[c4] = init_h4[c4];          // output row 0
    } else {
        c = fma4(sA[k - 1][j], c0, sB[k - 1][j]);
    }

    // ---------------- Phase 2: replay from registers, load only O ----------
    float4 orr[CL];
#pragma unroll
    for (int t = 0; t < CL; ++t) orr[t] = (yb + (size_t)t * ROWS4)[2 * HID4];

    float4* ob = out4 + (size_t)(k * CL + 1) * CH4 + c4;
#pragma unroll
    for (int t = 0; t < CL; ++t) {
        c = fma4(ff[t], c, gg[t]);
        float4 oo = sig4(orr[t]);
        ob[(size_t)t * CH4] = make_float4(c.x * oo.x, c.y * oo.y, c.z * oo.z, c.w * oo.w);
    }
}

extern "C" void kernel_launch(void* const* d_in, const int* in_sizes, int n_in,
                              void* d_out, int out_size, void* d_ws, size_t ws_size,
                              hipStream_t stream) {
    const float* Y      = (const float*)d_in[0];
    const float* init_c = (const float*)d_in[1];
    const float* init_h = (const float*)d_in[2];
    float* out = (float*)d_out;

    // 1024 blocks x 1024 threads; each block owns 32 channels across all T.
    fo_pool_fused<<<CH4 / JW, NTHR, 0, stream>>>(
        (const float4*)Y, (const float4*)init_c, (const float4*)init_h, (float4*)out);
}

// Round 9
// 307.489 us; speedup vs baseline: 1.0147x; 1.0147x over previous
//
#include <hip/hip_runtime.h>

// QRNN fo-pooling, single fused kernel, read-Y-once, 2-barrier scan.
// c_t = ff*c_{t-1} + gg, ff = sigmoid(F), gg = (1-ff)*tanh(Z), h_t = sigmoid(O)*c_t
// Block = 1024 thr = 128 chunks (CL=4 steps) x 8 float4-channel-groups.
// Phase 1: all 12 loads (F,Z,O) issued up-front; per-thread chunk affine (A,B);
//          ff,gg retained in registers.
// Combine: wave-level shuffle scan (8 chunks/wave) + LDS scan of 16 wave
//          aggregates -> exclusive prefix -> c_start per chunk. 2 barriers.
// Phase 2: replay from registers, write h. No loads after the scan.

#define T_SEQ 512
#define BATCH 32
#define HID   1024
#define CH    (BATCH * HID)        // 32768 channels
#define CH4   (CH / 4)             // 8192 float4 groups
#define HID4  (HID / 4)            // 256
#define ROWS4 (BATCH * 3 * HID4)   // float4 per t-step of Y
#define NC    128                  // chunks per block
#define CL    (T_SEQ / NC)         // 4 steps per chunk
#define JW    8                    // float4 channel-groups per block
#define NTHR  (NC * JW)            // 1024 threads
#define NWAVE (NTHR / 64)          // 16 waves; each wave = 8 chunks x 8 groups

__device__ __forceinline__ float fast_sigmoid(float x) {
    float e = __builtin_amdgcn_exp2f(-1.4426950408889634f * x);
    return __builtin_amdgcn_rcpf(1.0f + e);
}
__device__ __forceinline__ float fast_tanh(float x) {
    float e = __builtin_amdgcn_exp2f(-2.8853900817779268f * x);
    float s = __builtin_amdgcn_rcpf(1.0f + e);
    return __builtin_fmaf(2.0f, s, -1.0f);
}
__device__ __forceinline__ float4 sig4(float4 v) {
    return make_float4(fast_sigmoid(v.x), fast_sigmoid(v.y),
                       fast_sigmoid(v.z), fast_sigmoid(v.w));
}
__device__ __forceinline__ float4 fma4(float4 a, float4 b, float4 c) {
    return make_float4(__builtin_fmaf(a.x, b.x, c.x), __builtin_fmaf(a.y, b.y, c.y),
                       __builtin_fmaf(a.z, b.z, c.z), __builtin_fmaf(a.w, b.w, c.w));
}
__device__ __forceinline__ float4 mul4(float4 a, float4 b) {
    return make_float4(a.x * b.x, a.y * b.y, a.z * b.z, a.w * b.w);
}
__device__ __forceinline__ float4 shflup4(float4 v, int delta) {
    return make_float4(__shfl_up(v.x, delta, 64), __shfl_up(v.y, delta, 64),
                       __shfl_up(v.z, delta, 64), __shfl_up(v.w, delta, 64));
}

__global__ __launch_bounds__(NTHR) void fo_pool_fused(
        const float4* __restrict__ Y4,
        const float4* __restrict__ init_c4,
        const float4* __restrict__ init_h4,
        float4* __restrict__ out4) {
    __shared__ float4 sWA[NWAVE][JW];   // wave-aggregate affines (2 KB)
    __shared__ float4 sWB[NWAVE][JW];   // (2 KB)

    const int tid = threadIdx.x;
    const int j   = tid & (JW - 1);      // channel-group [0,8)
    const int k   = tid >> 3;            // chunk [0,128)
    const int kl  = k & 7;               // chunk-within-wave [0,8)
    const int w   = tid >> 6;            // wave [0,16)
    const int c4  = blockIdx.x * JW + j;
    const int b   = c4 >> 8;
    const int h4  = c4 & (HID4 - 1);
    const float4* yb = Y4 + b * (3 * HID4) + h4 + (size_t)(k * CL) * ROWS4;

    // ---- Phase 1: issue ALL loads up-front (F,Z,O + init_c), then gates ----
    float4 fr[CL], zr[CL], orr[CL];
#pragma unroll
    for (int t = 0; t < CL; ++t) {
        const float4* p = yb + (size_t)t * ROWS4;
        fr[t] = p[0]; zr[t] = p[HID4]; orr[t] = p[2 * HID4];
    }
    const float4 c0 = init_c4[c4];

    float4 ff[CL], gg[CL];
    float4 A  = make_float4(1.f, 1.f, 1.f, 1.f);
    float4 Bv = make_float4(0.f, 0.f, 0.f, 0.f);
#pragma unroll
    for (int t = 0; t < CL; ++t) {
        float4 s = sig4(fr[t]);
        float4 g;
        g.x = (1.f - s.x) * fast_tanh(zr[t].x);
        g.y = (1.f - s.y) * fast_tanh(zr[t].y);
        g.z = (1.f - s.z) * fast_tanh(zr[t].z);
        g.w = (1.f - s.w) * fast_tanh(zr[t].w);
        ff[t] = s; gg[t] = g;
        Bv = fma4(s, Bv, g);
        A  = mul4(A, s);
    }

    // ---- Combine A: within-wave inclusive scan over 8 chunks (shuffles) ----
    // lane = kl*8 + j; chunk k-d lives at lane - 8*d (same wave).
#pragma unroll
    for (int d = 1; d < 8; d <<= 1) {
        float4 pa = shflup4(A, 8 * d);
        float4 pb = shflup4(Bv, 8 * d);
        if (kl >= d) {
            Bv = fma4(A, pb, Bv);    // uses pre-update A
            A  = mul4(A, pa);
        }
    }

    // ---- Combine B: exclusive scan of 16 wave aggregates in LDS -----------
    if (kl == 7) { sWA[w][j] = A; sWB[w][j] = Bv; }   // wave-inclusive aggregate
    __syncthreads();
    if (tid < JW) {                                   // 8 threads, j = tid
        float4 RA = make_float4(1.f, 1.f, 1.f, 1.f);
        float4 RB = make_float4(0.f, 0.f, 0.f, 0.f);
#pragma unroll
        for (int ww = 0; ww < NWAVE; ++ww) {
            float4 ta = sWA[ww][tid], tb = sWB[ww][tid];
            sWA[ww][tid] = RA; sWB[ww][tid] = RB;     // exclusive prefix
            RB = fma4(ta, RB, tb);
            RA = mul4(ta, RA);
        }
    }
    __syncthreads();

    // ---- c_start for chunk k = I_{kl-1}( E_w( c0 ) ) ----------------------
    float4 cpre = fma4(sWA[w][j], c0, sWB[w][j]);     // apply waves < w
    float4 qa = shflup4(A, 8), qb = shflup4(Bv, 8);   // I_{kl-1} from lane-8
    float4 c  = (kl == 0) ? cpre : fma4(qa, cpre, qb);

    if (k == 0) out4[c4] = init_h4[c4];               // output row 0

    // ---- Phase 2: replay from registers, write h --------------------------
    float4* ob = out4 + (size_t)(k * CL + 1) * CH4 + c4;
#pragma unroll
    for (int t = 0; t < CL; ++t) {
        c = fma4(ff[t], c, gg[t]);
        float4 oo = sig4(orr[t]);
        ob[(size_t)t * CH4] = make_float4(c.x * oo.x, c.y * oo.y,
                                          c.z * oo.z, c.w * oo.w);
    }
}

extern "C" void kernel_launch(void* const* d_in, const int* in_sizes, int n_in,
                              void* d_out, int out_size, void* d_ws, size_t ws_size,
                              hipStream_t stream) {
    const float* Y      = (const float*)d_in[0];
    const float* init_c = (const float*)d_in[1];
    const float* init_h = (const float*)d_in[2];
    float* out = (float*)d_out;

    // 1024 blocks x 1024 threads; each block owns 32 channels across all T.
    fo_pool_fused<<<CH4 / JW, NTHR, 0, stream>>>(
        (const float4*)Y, (const float4*)init_c, (const float4*)init_h, (float4*)out);
}